// Round 4
// baseline (1108.979 us; speedup 1.0000x reference)
//
#include <hip/hip_runtime.h>
#include <hip/hip_bf16.h>

#define S_LEN 2048
#define HIDN  4096
#define NH    32
#define HD    128

typedef __attribute__((ext_vector_type(8))) __bf16 bf16x8;
typedef __attribute__((ext_vector_type(4))) float  f32x4;
typedef unsigned short u16;

__device__ __forceinline__ float bf2f(u16 u) {
  unsigned v = ((unsigned)u) << 16;
  return __builtin_bit_cast(float, v);
}
__device__ __forceinline__ u16 f2bf(float f) {
  unsigned u = __builtin_bit_cast(unsigned, f);
  u += 0x7FFFu + ((u >> 16) & 1u);
  return (u16)(u >> 16);
}
__device__ __forceinline__ float fexp2(float x) {   // 2^x, single v_exp_f32
  float r; asm("v_exp_f32 %0, %1" : "=v"(r) : "v"(x)); return r;
}
__device__ __forceinline__ void gload16(const void* g, void* l) {
  __builtin_amdgcn_global_load_lds((const __attribute__((address_space(1))) void*)g,
                                   (__attribute__((address_space(3))) void*)l, 16, 0, 0);
}
#define MFMA16(a, b, c) __builtin_amdgcn_mfma_f32_16x16x32_bf16(a, b, c, 0, 0, 0)

// ---------------- prep kernels ----------------

// f32 [R][C] -> bf16 [C][R]
__global__ void transpose_cast(const float* __restrict__ in, u16* __restrict__ out,
                               int R, int C) {
  __shared__ float t[32][33];
  const int c0 = blockIdx.x * 32, r0 = blockIdx.y * 32;
  const int tx = threadIdx.x, ty = threadIdx.y;
#pragma unroll
  for (int i = 0; i < 4; ++i)
    t[ty + i * 8][tx] = in[(size_t)(r0 + ty + i * 8) * C + c0 + tx];
  __syncthreads();
#pragma unroll
  for (int i = 0; i < 4; ++i)
    out[(size_t)(c0 + ty + i * 8) * R + r0 + tx] = f2bf(t[tx][ty + i * 8]);
}

struct u16x4s { u16 x, y, z, w; };

__global__ void cast_bf16_k(const float* __restrict__ in, u16* __restrict__ out, int n4) {
  int i = blockIdx.x * 256 + threadIdx.x;
  if (i < n4) {
    float4 v = ((const float4*)in)[i];
    u16x4s o;
    o.x = f2bf(v.x); o.y = f2bf(v.y); o.z = f2bf(v.z); o.w = f2bf(v.w);
    ((u16x4s*)out)[i] = o;
  }
}

__global__ void rope_table_k(const int* __restrict__ pos, float* __restrict__ cs,
                             float* __restrict__ sn) {
  int idx = blockIdx.x * 256 + threadIdx.x;   // S_LEN*64 total
  int s = idx >> 6, d = idx & 63;
  float inv = exp2f((-(float)d / 64.f) * 13.287712379549449f); // log2(10000)
  float ang = (float)pos[s] * inv;
  cs[idx] = cosf(ang);
  sn[idx] = sinf(ang);
}

// qkv bf16 [B*S][3*HIDN] -> roped Q,K bf16 [B,H,S,D]
// Q gets scale/sqrt(D) * log2(e) folded in (softmax runs in exp2 domain).
__global__ void rope_apply(const u16* __restrict__ qkv, const float* __restrict__ cs,
                           const float* __restrict__ sn, u16* __restrict__ Q,
                           u16* __restrict__ K) {
  const int row = blockIdx.x;            // b*S + s
  const int b = row >> 11, s = row & 2047;
  const u16* src = qkv + (size_t)row * (3 * HIDN);
#pragma unroll
  for (int it = 0; it < 2; ++it) {
    int idx = it * 256 + threadIdx.x;    // 512 = 2 which * 32 h * 8 groups
    int which = idx >> 8, h = (idx >> 3) & 31, d0 = (idx & 7) * 8;
    const u16* sp = src + which * HIDN + h * HD + d0;
    bf16x8 v1 = *(const bf16x8*)sp;
    bf16x8 v2 = *(const bf16x8*)(sp + 64);
    float4 c0 = *(const float4*)&cs[s * 64 + d0];
    float4 c1 = *(const float4*)&cs[s * 64 + d0 + 4];
    float4 s0 = *(const float4*)&sn[s * 64 + d0];
    float4 s1 = *(const float4*)&sn[s * 64 + d0 + 4];
    const float sc = which ? 1.0f : 0.12751743f;  // (1/sqrt(128))*log2(e) in Q
    bf16x8 r1, r2;
#pragma unroll
    for (int j = 0; j < 8; ++j) {
      float x1 = (float)v1[j], x2 = (float)v2[j];
      float cj = (j < 4) ? c0[j & 3] : c1[j & 3];
      float sj = (j < 4) ? s0[j & 3] : s1[j & 3];
      r1[j] = (__bf16)((x1 * cj - x2 * sj) * sc);
      r2[j] = (__bf16)((x2 * cj + x1 * sj) * sc);
    }
    u16* dst = (which ? K : Q) + ((size_t)(b * NH + h) * S_LEN + s) * HD + d0;
    *(bf16x8*)dst = r1;
    *(bf16x8*)(dst + 64) = r2;
  }
}

// V part of qkv -> Vt bf16 [B,H,D,S]
__global__ void v_transpose(const u16* __restrict__ qkv, u16* __restrict__ Vt) {
  __shared__ u16 t[32][33];
  const int bh = blockIdx.z;
  const int b = bh >> 5, h = bh & 31;
  const int s0 = blockIdx.x * 32, d0 = blockIdx.y * 32;
  const int tx = threadIdx.x, ty = threadIdx.y;
  const u16* src = qkv + (size_t)(b * S_LEN + s0) * (3 * HIDN) + 2 * HIDN + h * HD + d0;
#pragma unroll
  for (int i = 0; i < 4; ++i)
    t[ty + i * 8][tx] = src[(size_t)(ty + i * 8) * (3 * HIDN) + tx];
  __syncthreads();
  u16* dst = Vt + ((size_t)bh * HD + d0) * S_LEN + s0;
#pragma unroll
  for (int i = 0; i < 4; ++i)
    dst[(size_t)(ty + i * 8) * S_LEN + tx] = t[tx][ty + i * 8];
}

// ---------------- 256x256 8-phase GEMM: C[M][N] = A[M][K] * Bt[N][K]^T + bias ----
// (unchanged from round 3 — 46% MfmaUtil, 0 bank conflicts)
template <int OUT_BF16>
__global__ __launch_bounds__(512) void gemm256(
    const u16* __restrict__ A, const u16* __restrict__ Bt,
    const float* __restrict__ bias, void* __restrict__ Cv,
    int M, int N, int K, int nbx) {
  __shared__ alignas(16) u16 lds[2][2][2][128 * 64];
  const int tid = threadIdx.x;
  const int cpx = gridDim.x >> 3;
  const int swz = (blockIdx.x & 7) * cpx + (blockIdx.x >> 3);   // bijective (nb%8==0)
  const int bm = (swz / nbx) * 256, bn = (swz % nbx) * 256;
  const int w = tid >> 6, l = tid & 63;
  const int wm = w >> 2, wn = w & 3;
  const int lr = l & 15, lg = l >> 4;
  const int rswz = (lr & 7) * 8;                  // read-side XOR (u16 units)
  const int rl = tid >> 3;                        // staging row (per 8 threads)
  const int sl = (tid & 7) ^ ((tid >> 3) & 7);    // staging source slot (inverse swz)
  const u16* Ap = A + (size_t)bm * K;
  const u16* Bp = Bt + (size_t)bn * K;

#define STG(buf, ab, half, kt) do { \
    const u16* s_ = (ab ? Bp : Ap) + (size_t)((half) * 128 + rl) * K + (kt) * 64 + sl * 8; \
    u16* d_ = &lds[buf][ab][half][tid * 8]; \
    gload16(s_, d_); \
    gload16(s_ + (size_t)64 * K, d_ + 4096); \
  } while (0)

  f32x4 acc[8][4] = {};
  STG(0, 0, 0, 0); STG(0, 0, 1, 0); STG(0, 1, 0, 0); STG(0, 1, 1, 0);
  STG(1, 0, 0, 1); STG(1, 0, 1, 1);
  asm volatile("s_waitcnt vmcnt(4)" ::: "memory");   // K-tile 0 landed
  __builtin_amdgcn_s_barrier();

  const int NT = K >> 6;
  bf16x8 alo[4][2], ahi[4][2], bfr[2][2];
  for (int t = 0; t < NT; ++t) {
    const int buf = t & 1;
    const u16* Al = &lds[buf][0][wm][0];
    const u16* Bl = &lds[buf][1][wn >> 1][0];
    const int brow = (wn & 1) * 64;
    // ---------- phase 1 ----------
#pragma unroll
    for (int mi = 0; mi < 4; ++mi)
#pragma unroll
      for (int ks = 0; ks < 2; ++ks)
        alo[mi][ks] = *(const bf16x8*)&Al[(mi * 16 + lr) * 64 + ((ks * 32 + lg * 8) ^ rswz)];
#pragma unroll
    for (int ni = 0; ni < 2; ++ni)
#pragma unroll
      for (int ks = 0; ks < 2; ++ks)
        bfr[ni][ks] = *(const bf16x8*)&Bl[(brow + ni * 16 + lr) * 64 + ((ks * 32 + lg * 8) ^ rswz)];
    if (t + 1 < NT) STG(buf ^ 1, 1, 0, t + 1);
    __builtin_amdgcn_s_barrier();
    __builtin_amdgcn_s_setprio(1);
#pragma unroll
    for (int mi = 0; mi < 4; ++mi)
#pragma unroll
      for (int ni = 0; ni < 2; ++ni)
#pragma unroll
        for (int ks = 0; ks < 2; ++ks)
          acc[mi][ni] = MFMA16(alo[mi][ks], bfr[ni][ks], acc[mi][ni]);
    __builtin_amdgcn_s_setprio(0);
    __builtin_amdgcn_s_barrier();
    // ---------- phase 2 ----------
#pragma unroll
    for (int mi = 0; mi < 4; ++mi)
#pragma unroll
      for (int ks = 0; ks < 2; ++ks)
        ahi[mi][ks] = *(const bf16x8*)&Al[((mi + 4) * 16 + lr) * 64 + ((ks * 32 + lg * 8) ^ rswz)];
    if (t + 1 < NT) STG(buf ^ 1, 1, 1, t + 1);
    __builtin_amdgcn_s_barrier();
    __builtin_amdgcn_s_setprio(1);
#pragma unroll
    for (int mi = 0; mi < 4; ++mi)
#pragma unroll
      for (int ni = 0; ni < 2; ++ni)
#pragma unroll
        for (int ks = 0; ks < 2; ++ks)
          acc[mi + 4][ni] = MFMA16(ahi[mi][ks], bfr[ni][ks], acc[mi + 4][ni]);
    __builtin_amdgcn_s_setprio(0);
    __builtin_amdgcn_s_barrier();
    // ---------- phase 3 ----------
#pragma unroll
    for (int ni = 0; ni < 2; ++ni)
#pragma unroll
      for (int ks = 0; ks < 2; ++ks)
        bfr[ni][ks] = *(const bf16x8*)&Bl[(brow + (ni + 2) * 16 + lr) * 64 + ((ks * 32 + lg * 8) ^ rswz)];
    if (t + 2 < NT) STG(buf, 0, 0, t + 2);
    __builtin_amdgcn_s_barrier();
    __builtin_amdgcn_s_setprio(1);
#pragma unroll
    for (int mi = 0; mi < 4; ++mi)
#pragma unroll
      for (int ni = 0; ni < 2; ++ni)
#pragma unroll
        for (int ks = 0; ks < 2; ++ks)
          acc[mi][ni + 2] = MFMA16(alo[mi][ks], bfr[ni][ks], acc[mi][ni + 2]);
    __builtin_amdgcn_s_setprio(0);
    __builtin_amdgcn_s_barrier();
    // ---------- phase 4 ----------
    if (t + 2 < NT) {
      STG(buf, 0, 1, t + 2);
      asm volatile("s_waitcnt vmcnt(4)" ::: "memory");  // all of K-tile t+1 landed
    } else {
      asm volatile("s_waitcnt vmcnt(0)" ::: "memory");
    }
    __builtin_amdgcn_s_barrier();
    __builtin_amdgcn_s_setprio(1);
#pragma unroll
    for (int mi = 0; mi < 4; ++mi)
#pragma unroll
      for (int ni = 0; ni < 2; ++ni)
#pragma unroll
        for (int ks = 0; ks < 2; ++ks)
          acc[mi + 4][ni + 2] = MFMA16(ahi[mi][ks], bfr[ni][ks], acc[mi + 4][ni + 2]);
    __builtin_amdgcn_s_setprio(0);
    __builtin_amdgcn_s_barrier();
  }
#undef STG

#pragma unroll
  for (int ni = 0; ni < 4; ++ni) {
    const int col = bn + wn * 64 + ni * 16 + lr;
    const float bv = bias[col];
#pragma unroll
    for (int mi = 0; mi < 8; ++mi) {
      const int row = bm + wm * 128 + mi * 16 + lg * 4;
#pragma unroll
      for (int r = 0; r < 4; ++r) {
        float v = acc[mi][ni][r] + bv;
        if (OUT_BF16) ((u16*)Cv)[(size_t)(row + r) * N + col] = f2bf(v);
        else          ((float*)Cv)[(size_t)(row + r) * N + col] = v;
      }
    }
  }
}

// ---------------- causal flash attention ----------------
// 4 waves/block; block owns QBLK=128 q rows of one (b,h): two 64-row tiles
// processed sequentially per KV-step (wave w owns rows t*64 + w*16 .. +16).
// KVBLK=64, K/V double-buffered in LDS (XOR-swizzled). exp2-domain softmax
// (log2e folded into Q), defer-max THR=8, wave-uniform causal skips.
__global__ __launch_bounds__(256) void attn_k(
    const u16* __restrict__ Q, const u16* __restrict__ K,
    const u16* __restrict__ Vt, u16* __restrict__ O) {
  __shared__ alignas(16) u16 kbuf[2][64 * 128];
  __shared__ alignas(16) u16 vbuf[2][128 * 64];
  __shared__ alignas(16) u16 plds[4][16 * 64];
  const int blk = blockIdx.x;
  const int qb = blk & 15, h = (blk >> 4) & 31, b = blk >> 9;
  const int tid = threadIdx.x;
  const int w = tid >> 6, l = tid & 63;
  const int lr = l & 15, lg = l >> 4;
  const size_t bh = (size_t)(b * NH + h);
  const u16* Qp = Q + (bh * S_LEN + (size_t)qb * 128 + (size_t)w * 16) * HD;
  const u16* Kp = K + bh * S_LEN * HD;
  const u16* Vp = Vt + bh * HD * S_LEN;

  bf16x8 qf[2][4];
#pragma unroll
  for (int t = 0; t < 2; ++t)
#pragma unroll
    for (int kd = 0; kd < 4; ++kd)
      qf[t][kd] = *(const bf16x8*)&Qp[(t * 64 + lr) * HD + kd * 32 + lg * 8];

  f32x4 oacc[2][8] = {};
  float m[2][4], lsum[2][4];
#pragma unroll
  for (int t = 0; t < 2; ++t)
#pragma unroll
    for (int r = 0; r < 4; ++r) { m[t][r] = -1e30f; lsum[t][r] = 0.f; }
  const int nsteps = 2 * qb + 2;

#define ASTAGE(buf, kv0) do { \
    _Pragma("unroll") \
    for (int c = 0; c < 4; ++c) { \
      const int kr = c * 16 + (tid >> 4); \
      const int kc = ((tid & 15) * 8) ^ ((kr & 7) << 3); \
      gload16(Kp + (size_t)((kv0) + kr) * HD + kc, &kbuf[buf][c * 2048 + tid * 8]); \
      const int vr = c * 32 + (tid >> 3); \
      const int vc = ((tid & 7) * 8) ^ ((vr & 7) << 3); \
      gload16(Vp + (size_t)vr * S_LEN + (kv0) + vc, &vbuf[buf][c * 2048 + tid * 8]); \
    } \
  } while (0)

  ASTAGE(0, 0);
  for (int st = 0; st < nsteps; ++st) {
    const int kv0 = st * 64;
    const int cur = st & 1;
    __syncthreads();                       // stage(cur) landed; buf cur^1 free
    if (st + 1 < nsteps) ASTAGE(cur ^ 1, kv0 + 64);

#pragma unroll
    for (int t = 0; t < 2; ++t) {
      const int qmaxw = qb * 128 + t * 64 + w * 16 + 15;   // wave-uniform
      if (kv0 > qmaxw) continue;                           // tile fully masked
      const int na0 = ((qmaxw - kv0) >> 4) + 1;
      const int na = na0 > 4 ? 4 : na0;                    // active n-blocks
      const int qrow0 = qb * 128 + t * 64 + w * 16 + lg * 4;

      // ---- QK^T (only active n-blocks) ----
      f32x4 sacc[4] = {};
#pragma unroll
      for (int n = 0; n < 4; ++n) {
        if (n < na) {
          const int krow = n * 16 + lr;
          const int swzk = (krow & 7) << 3;
#pragma unroll
          for (int kd = 0; kd < 4; ++kd) {
            const bf16x8 kf = *(const bf16x8*)&kbuf[cur][krow * 128 + ((kd * 32 + lg * 8) ^ swzk)];
            sacc[n] = MFMA16(qf[t][kd], kf, sacc[n]);
          }
        }
      }
      // ---- causal mask ----
      float sv[4][4];
#pragma unroll
      for (int n = 0; n < 4; ++n) {
        const int col = kv0 + n * 16 + lr;
#pragma unroll
        for (int r = 0; r < 4; ++r)
          sv[n][r] = (col <= qrow0 + r) ? sacc[n][r] : -1e30f;
      }
      // ---- row max + defer-max ----
      float vmx[4];
#pragma unroll
      for (int r = 0; r < 4; ++r) {
        float v = fmaxf(fmaxf(sv[0][r], sv[1][r]), fmaxf(sv[2][r], sv[3][r]));
#pragma unroll
        for (int off = 1; off < 16; off <<= 1)
          v = fmaxf(v, __shfl_xor(v, off, 16));
        vmx[r] = v;
      }
      bool ok = true;
#pragma unroll
      for (int r = 0; r < 4; ++r) ok &= (vmx[r] <= m[t][r] + 8.f);
      if (!__all(ok)) {
        float al[4];
#pragma unroll
        for (int r = 0; r < 4; ++r) {
          float mn = fmaxf(m[t][r], vmx[r]);
          al[r] = fexp2(m[t][r] - mn);
          m[t][r] = mn;
          lsum[t][r] *= al[r];
        }
#pragma unroll
        for (int db = 0; db < 8; ++db)
#pragma unroll
          for (int r = 0; r < 4; ++r)
            oacc[t][db][r] *= al[r];
      }
      // ---- P = 2^(sv-m), write to LDS, row-sum ----
#pragma unroll
      for (int r = 0; r < 4; ++r) {
        const int prow = lg * 4 + r;
        const int pswz = (prow & 7) << 3;
        float ps = 0.f;
#pragma unroll
        for (int n = 0; n < 4; ++n) {
          float p = fexp2(sv[n][r] - m[t][r]);
          plds[w][prow * 64 + ((n * 16 + lr) ^ pswz)] = f2bf(p);
          ps += p;
        }
#pragma unroll
        for (int off = 1; off < 16; off <<= 1)
          ps += __shfl_xor(ps, off, 16);
        lsum[t][r] += ps;
      }
      // ---- PV (skip fully-masked 32-col halves) ----
#pragma unroll
      for (int ks = 0; ks < 2; ++ks) {
        if (kv0 + ks * 32 > qmaxw) continue;   // wave-uniform, P==0 there
        const bf16x8 pf = *(const bf16x8*)&plds[w][lr * 64 + ((ks * 32 + lg * 8) ^ ((lr & 7) << 3))];
#pragma unroll
        for (int db = 0; db < 8; ++db) {
          const int vrow = db * 16 + lr;
          const bf16x8 vf = *(const bf16x8*)&vbuf[cur][vrow * 64 + ((ks * 32 + lg * 8) ^ ((vrow & 7) << 3))];
          oacc[t][db] = MFMA16(pf, vf, oacc[t][db]);
        }
      }
    }
  }
#undef ASTAGE

  u16* Op = O + ((size_t)b * S_LEN + (size_t)qb * 128 + (size_t)w * 16) * HIDN + h * HD;
#pragma unroll
  for (int t = 0; t < 2; ++t)
#pragma unroll
    for (int db = 0; db < 8; ++db)
#pragma unroll
      for (int r = 0; r < 4; ++r)
        Op[(size_t)(t * 64 + lg * 4 + r) * HIDN + db * 16 + lr] = f2bf(oacc[t][db][r] / lsum[t][r]);
}

// ---------------- launcher ----------------
extern "C" void kernel_launch(void* const* d_in, const int* in_sizes, int n_in,
                              void* d_out, int out_size, void* d_ws, size_t ws_size,
                              hipStream_t stream) {
  const int*   positions = (const int*)d_in[0];
  const float* hidden    = (const float*)d_in[1];
  const float* Wqkv      = (const float*)d_in[2];
  const float* bqkv      = (const float*)d_in[3];
  const float* Wo        = (const float*)d_in[4];
  const float* bo        = (const float*)d_in[5];
  float* out = (float*)d_out;
  char* ws = (char*)d_ws;

  // workspace layout (bytes)
  u16*   WqkvT = (u16*)(ws + 0);            // [12288][4096] bf16, 96 MiB
  u16*   WoT   = (u16*)(ws + 100663296);    // [4096][4096] bf16, 32 MiB
  u16*   Xb    = (u16*)(ws + 134217728);    // [4096][4096] bf16, 32 MiB
  float* cosT  = (float*)(ws + 167772160);  // [2048][64] f32
  float* sinT  = (float*)(ws + 168296448);
  u16*   QKV   = (u16*)(ws + 168820736);    // [4096][12288] bf16, 96 MiB
  // aliases: WqkvT dead after GEMM1 -> holds Q,K,Vt ; Xb dead after GEMM1 -> holds O
  u16* Qr  = WqkvT;
  u16* Kr  = WqkvT + 16777216;
  u16* Vtr = WqkvT + 33554432;
  u16* Ob  = Xb;

  transpose_cast<<<dim3(384, 128), dim3(32, 8), 0, stream>>>(Wqkv, WqkvT, 4096, 12288);
  transpose_cast<<<dim3(128, 128), dim3(32, 8), 0, stream>>>(Wo, WoT, 4096, 4096);
  cast_bf16_k<<<16384, 256, 0, stream>>>(hidden, Xb, 4194304);
  rope_table_k<<<512, 256, 0, stream>>>(positions, cosT, sinT);
  gemm256<1><<<768, 512, 0, stream>>>(Xb, WqkvT, bqkv, QKV, 4096, 12288, 4096, 48);
  rope_apply<<<4096, 256, 0, stream>>>(QKV, cosT, sinT, Qr, Kr);
  v_transpose<<<dim3(64, 4, 64), dim3(32, 8), 0, stream>>>(QKV, Vtr);
  attn_k<<<1024, 256, 0, stream>>>(Qr, Kr, Vtr, Ob);
  gemm256<0><<<256, 512, 0, stream>>>(Ob, WoT, bo, out, 4096, 4096, 4096, 16);
}

// Round 5
// 812.776 us; speedup vs baseline: 1.3644x; 1.3644x over previous
//
#include <hip/hip_runtime.h>
#include <hip/hip_bf16.h>

#define S_LEN 2048
#define HIDN  4096
#define NH    32
#define HD    128

typedef __attribute__((ext_vector_type(8))) __bf16 bf16x8;
typedef __attribute__((ext_vector_type(4))) float  f32x4;
typedef unsigned short u16;

__device__ __forceinline__ float bf2f(u16 u) {
  unsigned v = ((unsigned)u) << 16;
  return __builtin_bit_cast(float, v);
}
__device__ __forceinline__ u16 f2bf(float f) {
  unsigned u = __builtin_bit_cast(unsigned, f);
  u += 0x7FFFu + ((u >> 16) & 1u);
  return (u16)(u >> 16);
}
__device__ __forceinline__ float fexp2(float x) {   // 2^x, single v_exp_f32
  float r; asm("v_exp_f32 %0, %1" : "=v"(r) : "v"(x)); return r;
}
__device__ __forceinline__ void gload16(const void* g, void* l) {
  __builtin_amdgcn_global_load_lds((const __attribute__((address_space(1))) void*)g,
                                   (__attribute__((address_space(3))) void*)l, 16, 0, 0);
}
#define MFMA16(a, b, c) __builtin_amdgcn_mfma_f32_16x16x32_bf16(a, b, c, 0, 0, 0)

// ---------------- prep kernels ----------------

// f32 [R][C] -> bf16 [C][R]
__global__ void transpose_cast(const float* __restrict__ in, u16* __restrict__ out,
                               int R, int C) {
  __shared__ float t[32][33];
  const int c0 = blockIdx.x * 32, r0 = blockIdx.y * 32;
  const int tx = threadIdx.x, ty = threadIdx.y;
#pragma unroll
  for (int i = 0; i < 4; ++i)
    t[ty + i * 8][tx] = in[(size_t)(r0 + ty + i * 8) * C + c0 + tx];
  __syncthreads();
#pragma unroll
  for (int i = 0; i < 4; ++i)
    out[(size_t)(c0 + ty + i * 8) * R + r0 + tx] = f2bf(t[tx][ty + i * 8]);
}

struct u16x4s { u16 x, y, z, w; };

__global__ void cast_bf16_k(const float* __restrict__ in, u16* __restrict__ out, int n4) {
  int i = blockIdx.x * 256 + threadIdx.x;
  if (i < n4) {
    float4 v = ((const float4*)in)[i];
    u16x4s o;
    o.x = f2bf(v.x); o.y = f2bf(v.y); o.z = f2bf(v.z); o.w = f2bf(v.w);
    ((u16x4s*)out)[i] = o;
  }
}

__global__ void rope_table_k(const int* __restrict__ pos, float* __restrict__ cs,
                             float* __restrict__ sn) {
  int idx = blockIdx.x * 256 + threadIdx.x;   // S_LEN*64 total
  int s = idx >> 6, d = idx & 63;
  float inv = exp2f((-(float)d / 64.f) * 13.287712379549449f); // log2(10000)
  float ang = (float)pos[s] * inv;
  cs[idx] = cosf(ang);
  sn[idx] = sinf(ang);
}

// qkv bf16 [B*S][3*HIDN] -> roped Q,K bf16 [B,H,S,D]
// Q gets scale/sqrt(D) * log2(e) folded in (softmax runs in exp2 domain).
__global__ void rope_apply(const u16* __restrict__ qkv, const float* __restrict__ cs,
                           const float* __restrict__ sn, u16* __restrict__ Q,
                           u16* __restrict__ K) {
  const int row = blockIdx.x;            // b*S + s
  const int b = row >> 11, s = row & 2047;
  const u16* src = qkv + (size_t)row * (3 * HIDN);
#pragma unroll
  for (int it = 0; it < 2; ++it) {
    int idx = it * 256 + threadIdx.x;    // 512 = 2 which * 32 h * 8 groups
    int which = idx >> 8, h = (idx >> 3) & 31, d0 = (idx & 7) * 8;
    const u16* sp = src + which * HIDN + h * HD + d0;
    bf16x8 v1 = *(const bf16x8*)sp;
    bf16x8 v2 = *(const bf16x8*)(sp + 64);
    float4 c0 = *(const float4*)&cs[s * 64 + d0];
    float4 c1 = *(const float4*)&cs[s * 64 + d0 + 4];
    float4 s0 = *(const float4*)&sn[s * 64 + d0];
    float4 s1 = *(const float4*)&sn[s * 64 + d0 + 4];
    const float sc = which ? 1.0f : 0.12751743f;  // (1/sqrt(128))*log2(e) in Q
    bf16x8 r1, r2;
#pragma unroll
    for (int j = 0; j < 8; ++j) {
      float x1 = (float)v1[j], x2 = (float)v2[j];
      float cj = (j < 4) ? c0[j & 3] : c1[j & 3];
      float sj = (j < 4) ? s0[j & 3] : s1[j & 3];
      r1[j] = (__bf16)((x1 * cj - x2 * sj) * sc);
      r2[j] = (__bf16)((x2 * cj + x1 * sj) * sc);
    }
    u16* dst = (which ? K : Q) + ((size_t)(b * NH + h) * S_LEN + s) * HD + d0;
    *(bf16x8*)dst = r1;
    *(bf16x8*)(dst + 64) = r2;
  }
}

// V part of qkv -> Vt bf16 [B,H,D,S]
__global__ void v_transpose(const u16* __restrict__ qkv, u16* __restrict__ Vt) {
  __shared__ u16 t[32][33];
  const int bh = blockIdx.z;
  const int b = bh >> 5, h = bh & 31;
  const int s0 = blockIdx.x * 32, d0 = blockIdx.y * 32;
  const int tx = threadIdx.x, ty = threadIdx.y;
  const u16* src = qkv + (size_t)(b * S_LEN + s0) * (3 * HIDN) + 2 * HIDN + h * HD + d0;
#pragma unroll
  for (int i = 0; i < 4; ++i)
    t[ty + i * 8][tx] = src[(size_t)(ty + i * 8) * (3 * HIDN) + tx];
  __syncthreads();
  u16* dst = Vt + ((size_t)bh * HD + d0) * S_LEN + s0;
#pragma unroll
  for (int i = 0; i < 4; ++i)
    dst[(size_t)(ty + i * 8) * S_LEN + tx] = t[tx][ty + i * 8];
}

// ---------------- 256x256 8-phase GEMM: C[M][N] = A[M][K] * Bt[N][K]^T + bias ----
// (unchanged — 46% MfmaUtil, 0 bank conflicts)
template <int OUT_BF16>
__global__ __launch_bounds__(512) void gemm256(
    const u16* __restrict__ A, const u16* __restrict__ Bt,
    const float* __restrict__ bias, void* __restrict__ Cv,
    int M, int N, int K, int nbx) {
  __shared__ alignas(16) u16 lds[2][2][2][128 * 64];
  const int tid = threadIdx.x;
  const int cpx = gridDim.x >> 3;
  const int swz = (blockIdx.x & 7) * cpx + (blockIdx.x >> 3);   // bijective (nb%8==0)
  const int bm = (swz / nbx) * 256, bn = (swz % nbx) * 256;
  const int w = tid >> 6, l = tid & 63;
  const int wm = w >> 2, wn = w & 3;
  const int lr = l & 15, lg = l >> 4;
  const int rswz = (lr & 7) * 8;                  // read-side XOR (u16 units)
  const int rl = tid >> 3;                        // staging row (per 8 threads)
  const int sl = (tid & 7) ^ ((tid >> 3) & 7);    // staging source slot (inverse swz)
  const u16* Ap = A + (size_t)bm * K;
  const u16* Bp = Bt + (size_t)bn * K;

#define STG(buf, ab, half, kt) do { \
    const u16* s_ = (ab ? Bp : Ap) + (size_t)((half) * 128 + rl) * K + (kt) * 64 + sl * 8; \
    u16* d_ = &lds[buf][ab][half][tid * 8]; \
    gload16(s_, d_); \
    gload16(s_ + (size_t)64 * K, d_ + 4096); \
  } while (0)

  f32x4 acc[8][4] = {};
  STG(0, 0, 0, 0); STG(0, 0, 1, 0); STG(0, 1, 0, 0); STG(0, 1, 1, 0);
  STG(1, 0, 0, 1); STG(1, 0, 1, 1);
  asm volatile("s_waitcnt vmcnt(4)" ::: "memory");   // K-tile 0 landed
  __builtin_amdgcn_s_barrier();

  const int NT = K >> 6;
  bf16x8 alo[4][2], ahi[4][2], bfr[2][2];
  for (int t = 0; t < NT; ++t) {
    const int buf = t & 1;
    const u16* Al = &lds[buf][0][wm][0];
    const u16* Bl = &lds[buf][1][wn >> 1][0];
    const int brow = (wn & 1) * 64;
    // ---------- phase 1 ----------
#pragma unroll
    for (int mi = 0; mi < 4; ++mi)
#pragma unroll
      for (int ks = 0; ks < 2; ++ks)
        alo[mi][ks] = *(const bf16x8*)&Al[(mi * 16 + lr) * 64 + ((ks * 32 + lg * 8) ^ rswz)];
#pragma unroll
    for (int ni = 0; ni < 2; ++ni)
#pragma unroll
      for (int ks = 0; ks < 2; ++ks)
        bfr[ni][ks] = *(const bf16x8*)&Bl[(brow + ni * 16 + lr) * 64 + ((ks * 32 + lg * 8) ^ rswz)];
    if (t + 1 < NT) STG(buf ^ 1, 1, 0, t + 1);
    __builtin_amdgcn_s_barrier();
    __builtin_amdgcn_s_setprio(1);
#pragma unroll
    for (int mi = 0; mi < 4; ++mi)
#pragma unroll
      for (int ni = 0; ni < 2; ++ni)
#pragma unroll
        for (int ks = 0; ks < 2; ++ks)
          acc[mi][ni] = MFMA16(alo[mi][ks], bfr[ni][ks], acc[mi][ni]);
    __builtin_amdgcn_s_setprio(0);
    __builtin_amdgcn_s_barrier();
    // ---------- phase 2 ----------
#pragma unroll
    for (int mi = 0; mi < 4; ++mi)
#pragma unroll
      for (int ks = 0; ks < 2; ++ks)
        ahi[mi][ks] = *(const bf16x8*)&Al[((mi + 4) * 16 + lr) * 64 + ((ks * 32 + lg * 8) ^ rswz)];
    if (t + 1 < NT) STG(buf ^ 1, 1, 1, t + 1);
    __builtin_amdgcn_s_barrier();
    __builtin_amdgcn_s_setprio(1);
#pragma unroll
    for (int mi = 0; mi < 4; ++mi)
#pragma unroll
      for (int ni = 0; ni < 2; ++ni)
#pragma unroll
        for (int ks = 0; ks < 2; ++ks)
          acc[mi + 4][ni] = MFMA16(ahi[mi][ks], bfr[ni][ks], acc[mi + 4][ni]);
    __builtin_amdgcn_s_setprio(0);
    __builtin_amdgcn_s_barrier();
    // ---------- phase 3 ----------
#pragma unroll
    for (int ni = 0; ni < 2; ++ni)
#pragma unroll
      for (int ks = 0; ks < 2; ++ks)
        bfr[ni][ks] = *(const bf16x8*)&Bl[(brow + (ni + 2) * 16 + lr) * 64 + ((ks * 32 + lg * 8) ^ rswz)];
    if (t + 2 < NT) STG(buf, 0, 0, t + 2);
    __builtin_amdgcn_s_barrier();
    __builtin_amdgcn_s_setprio(1);
#pragma unroll
    for (int mi = 0; mi < 4; ++mi)
#pragma unroll
      for (int ni = 0; ni < 2; ++ni)
#pragma unroll
        for (int ks = 0; ks < 2; ++ks)
          acc[mi][ni + 2] = MFMA16(alo[mi][ks], bfr[ni][ks], acc[mi][ni + 2]);
    __builtin_amdgcn_s_setprio(0);
    __builtin_amdgcn_s_barrier();
    // ---------- phase 4 ----------
    if (t + 2 < NT) {
      STG(buf, 0, 1, t + 2);
      asm volatile("s_waitcnt vmcnt(4)" ::: "memory");  // all of K-tile t+1 landed
    } else {
      asm volatile("s_waitcnt vmcnt(0)" ::: "memory");
    }
    __builtin_amdgcn_s_barrier();
    __builtin_amdgcn_s_setprio(1);
#pragma unroll
    for (int mi = 0; mi < 4; ++mi)
#pragma unroll
      for (int ni = 0; ni < 2; ++ni)
#pragma unroll
        for (int ks = 0; ks < 2; ++ks)
          acc[mi + 4][ni + 2] = MFMA16(ahi[mi][ks], bfr[ni][ks], acc[mi + 4][ni + 2]);
    __builtin_amdgcn_s_setprio(0);
    __builtin_amdgcn_s_barrier();
  }
#undef STG

#pragma unroll
  for (int ni = 0; ni < 4; ++ni) {
    const int col = bn + wn * 64 + ni * 16 + lr;
    const float bv = bias[col];
#pragma unroll
    for (int mi = 0; mi < 8; ++mi) {
      const int row = bm + wm * 128 + mi * 16 + lg * 4;
#pragma unroll
      for (int r = 0; r < 4; ++r) {
        float v = acc[mi][ni][r] + bv;
        if (OUT_BF16) ((u16*)Cv)[(size_t)(row + r) * N + col] = f2bf(v);
        else          ((float*)Cv)[(size_t)(row + r) * N + col] = v;
      }
    }
  }
}

// ---------------- causal flash attention ----------------
// R3 geometry: 4 waves/block, QBLK=64 (wave owns 16 rows), KVBLK=64, K/V
// double-buffered + XOR-swizzled in LDS. New: longest-first block remap
// (qb = 31 - (blk>>6)) to kill the load-imbalance tail; exp2-domain softmax
// (log2e in Q), defer-max THR=8, causal n-block / PV-half skips.
__global__ __launch_bounds__(256) void attn_k(
    const u16* __restrict__ Q, const u16* __restrict__ K,
    const u16* __restrict__ Vt, u16* __restrict__ O) {
  __shared__ alignas(16) u16 kbuf[2][64 * 128];
  __shared__ alignas(16) u16 vbuf[2][128 * 64];
  __shared__ alignas(16) u16 plds[4][16 * 64];
  const int blk = blockIdx.x;
  const int qb = 31 - (blk >> 6);          // longest blocks dispatch first
  const int bhid = blk & 63;
  const int b = bhid >> 5, h = bhid & 31;
  const int tid = threadIdx.x;
  const int w = tid >> 6, l = tid & 63;
  const int lr = l & 15, lg = l >> 4;
  const size_t bh = (size_t)(b * NH + h);
  const u16* Qp = Q + (bh * S_LEN + (size_t)qb * 64 + (size_t)w * 16) * HD;
  const u16* Kp = K + bh * S_LEN * HD;
  const u16* Vp = Vt + bh * HD * S_LEN;

  bf16x8 qf[4];
#pragma unroll
  for (int kd = 0; kd < 4; ++kd)
    qf[kd] = *(const bf16x8*)&Qp[lr * HD + kd * 32 + lg * 8];

  f32x4 oacc[8] = {};
  float m[4], lsum[4];
#pragma unroll
  for (int r = 0; r < 4; ++r) { m[r] = -1e30f; lsum[r] = 0.f; }
  const int nsteps = qb + 1;
  const int qmin = qb * 64 + w * 16;       // wave-uniform first q row
  const int qrow0 = qmin + lg * 4;

#define ASTAGE(buf, kv0) do { \
    _Pragma("unroll") \
    for (int c = 0; c < 4; ++c) { \
      const int kr = c * 16 + (tid >> 4); \
      const int kc = ((tid & 15) * 8) ^ ((kr & 7) << 3); \
      gload16(Kp + (size_t)((kv0) + kr) * HD + kc, &kbuf[buf][c * 2048 + tid * 8]); \
      const int vr = c * 32 + (tid >> 3); \
      const int vc = ((tid & 7) * 8) ^ ((vr & 7) << 3); \
      gload16(Vp + (size_t)vr * S_LEN + (kv0) + vc, &vbuf[buf][c * 2048 + tid * 8]); \
    } \
  } while (0)

  ASTAGE(0, 0);
  for (int st = 0; st < nsteps; ++st) {
    const int kv0 = st * 64;
    const int cur = st & 1;
    __syncthreads();                       // stage(cur) landed; buf cur^1 free
    if (st + 1 < nsteps) ASTAGE(cur ^ 1, kv0 + 64);

    const int qmaxw = qmin + 15;
    const int na0 = ((qmaxw - kv0) >> 4) + 1;
    const int na = na0 > 4 ? 4 : na0;      // active 16-col n-blocks (wave-uniform)

    // ---- QK^T (active n-blocks only) ----
    f32x4 sacc[4] = {};
#pragma unroll
    for (int n = 0; n < 4; ++n) {
      if (n < na) {
        const int krow = n * 16 + lr;
        const int swzk = (krow & 7) << 3;
#pragma unroll
        for (int kd = 0; kd < 4; ++kd) {
          const bf16x8 kf = *(const bf16x8*)&kbuf[cur][krow * 128 + ((kd * 32 + lg * 8) ^ swzk)];
          sacc[n] = MFMA16(qf[kd], kf, sacc[n]);
        }
      }
    }
    // ---- causal mask (skip when step fully below diagonal) ----
    float sv[4][4];
    if (kv0 + 63 <= qmin) {
#pragma unroll
      for (int n = 0; n < 4; ++n)
#pragma unroll
        for (int r = 0; r < 4; ++r) sv[n][r] = sacc[n][r];
    } else {
#pragma unroll
      for (int n = 0; n < 4; ++n) {
        const int col = kv0 + n * 16 + lr;
#pragma unroll
        for (int r = 0; r < 4; ++r)
          sv[n][r] = (col <= qrow0 + r) ? sacc[n][r] : -1e30f;
      }
    }
    // ---- row max + defer-max (THR=8 in exp2 domain) ----
    float vmx[4];
#pragma unroll
    for (int r = 0; r < 4; ++r) {
      float v = fmaxf(fmaxf(sv[0][r], sv[1][r]), fmaxf(sv[2][r], sv[3][r]));
#pragma unroll
      for (int off = 1; off < 16; off <<= 1)
        v = fmaxf(v, __shfl_xor(v, off, 16));
      vmx[r] = v;
    }
    bool ok = true;
#pragma unroll
    for (int r = 0; r < 4; ++r) ok &= (vmx[r] <= m[r] + 8.f);
    if (!__all(ok)) {
      float al[4];
#pragma unroll
      for (int r = 0; r < 4; ++r) {
        float mn = fmaxf(m[r], vmx[r]);
        al[r] = fexp2(m[r] - mn);
        m[r] = mn;
        lsum[r] *= al[r];
      }
#pragma unroll
      for (int db = 0; db < 8; ++db)
#pragma unroll
        for (int r = 0; r < 4; ++r)
          oacc[db][r] *= al[r];
    }
    // ---- P = 2^(sv-m), write to LDS, row-sum ----
#pragma unroll
    for (int r = 0; r < 4; ++r) {
      const int prow = lg * 4 + r;
      const int pswz = (prow & 7) << 3;
      float ps = 0.f;
#pragma unroll
      for (int n = 0; n < 4; ++n) {
        float p = fexp2(sv[n][r] - m[r]);
        plds[w][prow * 64 + ((n * 16 + lr) ^ pswz)] = f2bf(p);
        ps += p;
      }
#pragma unroll
      for (int off = 1; off < 16; off <<= 1)
        ps += __shfl_xor(ps, off, 16);
      lsum[r] += ps;
    }
    // ---- PV (skip fully-masked 32-col halves) ----
#pragma unroll
    for (int ks = 0; ks < 2; ++ks) {
      if (kv0 + ks * 32 > qmaxw) continue;   // wave-uniform, P==0 there
      const bf16x8 pf = *(const bf16x8*)&plds[w][lr * 64 + ((ks * 32 + lg * 8) ^ ((lr & 7) << 3))];
#pragma unroll
      for (int db = 0; db < 8; ++db) {
        const int vrow = db * 16 + lr;
        const bf16x8 vf = *(const bf16x8*)&vbuf[cur][vrow * 64 + ((ks * 32 + lg * 8) ^ ((vrow & 7) << 3))];
        oacc[db] = MFMA16(pf, vf, oacc[db]);
      }
    }
  }
#undef ASTAGE

  u16* Op = O + ((size_t)b * S_LEN + (size_t)qb * 64 + (size_t)w * 16) * HIDN + h * HD;
#pragma unroll
  for (int db = 0; db < 8; ++db)
#pragma unroll
    for (int r = 0; r < 4; ++r)
      Op[(size_t)(lg * 4 + r) * HIDN + db * 16 + lr] = f2bf(oacc[db][r] / lsum[r]);
}

// ---------------- launcher ----------------
extern "C" void kernel_launch(void* const* d_in, const int* in_sizes, int n_in,
                              void* d_out, int out_size, void* d_ws, size_t ws_size,
                              hipStream_t stream) {
  const int*   positions = (const int*)d_in[0];
  const float* hidden    = (const float*)d_in[1];
  const float* Wqkv      = (const float*)d_in[2];
  const float* bqkv      = (const float*)d_in[3];
  const float* Wo        = (const float*)d_in[4];
  const float* bo        = (const float*)d_in[5];
  float* out = (float*)d_out;
  char* ws = (char*)d_ws;

  // workspace layout (bytes)
  u16*   WqkvT = (u16*)(ws + 0);            // [12288][4096] bf16, 96 MiB
  u16*   WoT   = (u16*)(ws + 100663296);    // [4096][4096] bf16, 32 MiB
  u16*   Xb    = (u16*)(ws + 134217728);    // [4096][4096] bf16, 32 MiB
  float* cosT  = (float*)(ws + 167772160);  // [2048][64] f32
  float* sinT  = (float*)(ws + 168296448);
  u16*   QKV   = (u16*)(ws + 168820736);    // [4096][12288] bf16, 96 MiB
  // aliases: WqkvT dead after GEMM1 -> holds Q,K,Vt ; Xb dead after GEMM1 -> holds O
  u16* Qr  = WqkvT;
  u16* Kr  = WqkvT + 16777216;
  u16* Vtr = WqkvT + 33554432;
  u16* Ob  = Xb;

  transpose_cast<<<dim3(384, 128), dim3(32, 8), 0, stream>>>(Wqkv, WqkvT, 4096, 12288);
  transpose_cast<<<dim3(128, 128), dim3(32, 8), 0, stream>>>(Wo, WoT, 4096, 4096);
  cast_bf16_k<<<16384, 256, 0, stream>>>(hidden, Xb, 4194304);
  rope_table_k<<<512, 256, 0, stream>>>(positions, cosT, sinT);
  gemm256<1><<<768, 512, 0, stream>>>(Xb, WqkvT, bqkv, QKV, 4096, 12288, 4096, 48);
  rope_apply<<<4096, 256, 0, stream>>>(QKV, cosT, sinT, Qr, Kr);
  v_transpose<<<dim3(64, 4, 64), dim3(32, 8), 0, stream>>>(QKV, Vtr);
  attn_k<<<2048, 256, 0, stream>>>(Qr, Kr, Vtr, Ob);
  gemm256<0><<<256, 512, 0, stream>>>(Ob, WoT, bo, out, 4096, 4096, 4096, 16);
}